// Round 9
// baseline (361.021 us; speedup 1.0000x reference)
//
#include <hip/hip_runtime.h>
#include <stdint.h>

// AttentionBlock: GroupNorm(32) -> QKV -> full 4096x4096 attention per batch
// -> out projection + residual.  B=4, HW=4096, C=512.
// R13: per-kernel best-of-breed (each backed by >=2 replicated measurements).
//  - qkt: 128x128 dbuf engine, NO XCD swizzle, plain ushort4 stores
//    (112.7us R6 / 113.4us R11; the conflict-free 256x256 measured 137.7 in
//    R12 -- lockstep-burst theory -- and swizzle/NT variants all regressed).
//  - qkv: 256x256 8-phase engine WITH the (row>>1)&3 conflict-free swizzle
//    (R12's total win lives here; bank conflicts 6.29M -> 0 measured).
//  - pv: full-K=4096 128x128 dbuf, lsum division in epilogue (best measured).
//  - proj: 128x128 dbuf.  NB=4.

typedef __attribute__((ext_vector_type(8))) short bf16x8;
typedef __attribute__((ext_vector_type(8))) unsigned short u16x8;
typedef __attribute__((ext_vector_type(4))) float f32x4;

#define QSCALE 0.06376237087058025f           // 512^-0.5 * log2(e)

__device__ __forceinline__ unsigned short f2bf(float f) {
  unsigned int x = __float_as_uint(f);
  x += 0x7fffu + ((x >> 16) & 1u);
  return (unsigned short)(x >> 16);
}
__device__ __forceinline__ float bf2f(unsigned short u) {
  return __uint_as_float((unsigned int)u << 16);
}

__device__ __forceinline__ void gl_lds16(const void* g, void* l) {
  __builtin_amdgcn_global_load_lds(
      (__attribute__((address_space(1))) unsigned char*)g,
      (__attribute__((address_space(3))) unsigned char*)l, 16, 0, 0);
}

#define SBAR() asm volatile("s_barrier" ::: "memory")

// ======== 128x128 dbuf engine (R6): B col-remap, 2-phase pipeline ==========
// LDS 16B granules XOR-swizzled: A by (row&7), B by ((row>>2)&7).
// B fragment t covers cols wn + 4*lrow + t  =>  vectorized epilogues
// (acc[mt][t][r] = C[wm+mt*16+lrb+r][wn+4*lcol+t]).
__device__ __forceinline__ void gemm_tile(
    const unsigned short* __restrict__ A, long lda,
    const unsigned short* __restrict__ B, long ldb,
    int K,
    unsigned short* As0, unsigned short* As1,
    unsigned short* Bs0, unsigned short* Bs1,
    f32x4 acc[4][4]) {
  const int tid = threadIdx.x;
  const int wave = tid >> 6, lane = tid & 63;
  const int srow = lane >> 3;
  const int gg = lane & 7;
  const int wm = (wave >> 1) * 64, wn = (wave & 1) * 64;
  const int lrow = lane & 15;
  const int rsw = lrow & 7;
  const int kgb = lane >> 4;

  auto STAGE = [&](unsigned short* as, unsigned short* bs, int k0) {
#pragma unroll
    for (int i = 0; i < 4; ++i) {
      int chunk = wave * 4 + i;
      int row = chunk * 8 + srow;
      int soffA = (gg ^ srow) * 16;
      int soffB = (gg ^ ((chunk * 2 + (srow >> 2)) & 7)) * 16;
      gl_lds16((const char*)(A + (long)row * lda + k0) + soffA, (char*)as + chunk * 1024);
      gl_lds16((const char*)(B + (long)row * ldb + k0) + soffB, (char*)bs + chunk * 1024);
    }
  };

  auto COMPUTE = [&](const unsigned short* as, const unsigned short* bs) {
#pragma unroll
    for (int ks = 0; ks < 2; ++ks) {
      bf16x8 af[4], bfr[4];
      const int off = ((ks * 4 + kgb) ^ rsw) * 8;
#pragma unroll
      for (int t = 0; t < 4; ++t) {
        af[t]  = *(const bf16x8*)&as[(wm + t * 16 + lrow) * 64 + off];
        bfr[t] = *(const bf16x8*)&bs[(wn + 4 * lrow + t) * 64 + off];
      }
#pragma unroll
      for (int mt = 0; mt < 4; ++mt)
#pragma unroll
        for (int nt = 0; nt < 4; ++nt)
          acc[mt][nt] = __builtin_amdgcn_mfma_f32_16x16x32_bf16(af[mt], bfr[nt], acc[mt][nt], 0, 0, 0);
    }
  };

  const int nk = K >> 6;
  STAGE(As0, Bs0, 0);
  __syncthreads();
  for (int t = 0; t < nk; t += 2) {
    if (t + 1 < nk) STAGE(As1, Bs1, (t + 1) * 64);
    COMPUTE(As0, Bs0);
    __syncthreads();
    if (t + 2 < nk) STAGE(As0, Bs0, (t + 2) * 64);
    COMPUTE(As1, Bs1);
    __syncthreads();
  }
}

#define GEMM_SHARED                                              \
  __shared__ unsigned short As0[128 * 64], As1[128 * 64];        \
  __shared__ unsigned short Bs0[128 * 64], Bs1[128 * 64];

#define EPILOG_SETUP                                          \
  const int lane = threadIdx.x & 63, wave = threadIdx.x >> 6; \
  const int wm = (wave >> 1) * 64, wn = (wave & 1) * 64;      \
  const int lcol4 = (lane & 15) * 4, lrb = (lane >> 4) * 4;

// ================= 256x256 tile, BK=64, 2-dbuf K-halves, 8-phase ============
// Conflict-free swizzle: bank = (16*row + 4*slot) % 32; key = (row>>1)&3
// gives every bank exactly 2 lanes per 16-lane group (free, m136); key
// invariant under row+16/+64/+128 so one key serves staging and reads.
// Counted vmcnt(8) gates, never vmcnt(0) in steady state.
__device__ __forceinline__ void gemm256_tile(
    const unsigned short* __restrict__ A, long lda,
    const unsigned short* __restrict__ B, long ldb,
    int NT, unsigned short* lds, f32x4 acc[8][4]) {
  const int tid = threadIdx.x;
  const int wave = tid >> 6, lane = tid & 63;
  const int wm = wave >> 2, wn = wave & 3;
  const int lrow = lane & 15, kgb = lane >> 4;
  const int koff = (kgb ^ ((lrow >> 1) & 3)) * 8;       // key=(row>>1)&3
  const int srow = wave * 32 + (lane >> 2);
  const int sg = ((lane & 3) ^ ((lane >> 3) & 3)) * 8;  // key(srow>>1)&3 == (lane>>3)&3
  const int sdst = wave * 1024;

  auto STAGE = [&](int t, int kh, int isB) {
    const unsigned short* src = (isB ? B : A) + (long)t * 64 + kh * 32 + sg;
    long ld = isB ? ldb : lda;
    unsigned short* db = lds + isB * 32768 + ((t & 1) * 2 + kh) * 8192 + sdst;
    gl_lds16(src + (long)srow * ld, db);
    gl_lds16(src + (long)(srow + 16) * ld, db + 512);   // key(row+16)==key(row)
  };

  STAGE(0, 0, 0); STAGE(0, 0, 1);
  STAGE(0, 1, 0); STAGE(0, 1, 1);
  STAGE(1, 0, 0); STAGE(1, 0, 1);

  for (int T = 0; T < NT; ++T) {
    const int d2 = (T & 1) * 2;
    const unsigned short* aB = lds + d2 * 8192 + (wm * 128 + lrow) * 32 + koff;
    const unsigned short* bB = lds + 32768 + d2 * 8192 + ((wn & 1) * 64 + lrow) * 32 + koff;
    const bool more = (T + 1 < NT);
    bf16x8 a0[4], a1[4], b0[4];

    if (more) { asm volatile("s_waitcnt vmcnt(8)" ::: "memory"); }
    else      { asm volatile("s_waitcnt vmcnt(4)" ::: "memory"); }
    SBAR();

#pragma unroll
    for (int m = 0; m < 4; ++m) a0[m] = *(const bf16x8*)(aB + m * 512);
#pragma unroll
    for (int n = 0; n < 4; ++n) b0[n] = *(const bf16x8*)(bB + n * 512);
    if (more) STAGE(T + 1, 1, 0);
    SBAR();
    __builtin_amdgcn_s_setprio(1);
#pragma unroll
    for (int m = 0; m < 4; ++m)
#pragma unroll
      for (int n = 0; n < 4; ++n)
        acc[m][n] = __builtin_amdgcn_mfma_f32_16x16x32_bf16(a0[m], b0[n], acc[m][n], 0, 0, 0);
    __builtin_amdgcn_s_setprio(0);

#pragma unroll
    for (int m = 0; m < 4; ++m) a1[m] = *(const bf16x8*)(aB + (4 + m) * 512);
    if (more) STAGE(T + 1, 1, 1);
    SBAR();
    __builtin_amdgcn_s_setprio(1);
#pragma unroll
    for (int m = 0; m < 4; ++m)
#pragma unroll
      for (int n = 0; n < 4; ++n)
        acc[4 + m][n] = __builtin_amdgcn_mfma_f32_16x16x32_bf16(a1[m], b0[n], acc[4 + m][n], 0, 0, 0);
    __builtin_amdgcn_s_setprio(0);

    if (more) { asm volatile("s_waitcnt vmcnt(8)" ::: "memory"); }
    else      { asm volatile("s_waitcnt vmcnt(0)" ::: "memory"); }
    SBAR();

    const unsigned short* aB1 = aB + 8192;
    const unsigned short* bB1 = bB + 8192;
#pragma unroll
    for (int m = 0; m < 4; ++m) a0[m] = *(const bf16x8*)(aB1 + m * 512);
#pragma unroll
    for (int n = 0; n < 4; ++n) b0[n] = *(const bf16x8*)(bB1 + n * 512);
    if (T + 2 < NT) STAGE(T + 2, 0, 0);
    SBAR();
    __builtin_amdgcn_s_setprio(1);
#pragma unroll
    for (int m = 0; m < 4; ++m)
#pragma unroll
      for (int n = 0; n < 4; ++n)
        acc[m][n] = __builtin_amdgcn_mfma_f32_16x16x32_bf16(a0[m], b0[n], acc[m][n], 0, 0, 0);
    __builtin_amdgcn_s_setprio(0);
    SBAR();

#pragma unroll
    for (int m = 0; m < 4; ++m) a1[m] = *(const bf16x8*)(aB1 + (4 + m) * 512);
    if (T + 2 < NT) STAGE(T + 2, 0, 1);
    SBAR();
    __builtin_amdgcn_s_setprio(1);
#pragma unroll
    for (int m = 0; m < 4; ++m)
#pragma unroll
      for (int n = 0; n < 4; ++n)
        acc[4 + m][n] = __builtin_amdgcn_mfma_f32_16x16x32_bf16(a1[m], b0[n], acc[4 + m][n], 0, 0, 0);
    __builtin_amdgcn_s_setprio(0);
  }
}

// ---------------- prep: weights -> bf16 [N][K], bias pack, zero stats+l ----
__global__ void prep_kernel(const float* __restrict__ wq, const float* __restrict__ wk,
                            const float* __restrict__ wv, const float* __restrict__ wo,
                            const float* __restrict__ bq, const float* __restrict__ bk,
                            const float* __restrict__ bv,
                            unsigned short* __restrict__ wqkvT,
                            unsigned short* __restrict__ woT,
                            float* __restrict__ bias, float* __restrict__ stats,
                            float* __restrict__ lsum) {
  long id = (long)blockIdx.x * 256 + threadIdx.x;
  if (id < 786432) {                       // wqkvT[n][k]
    long n = id >> 9, k = id & 511;
    const float* w = (n < 512) ? wq : (n < 1024 ? wk : wv);
    wqkvT[id] = f2bf(w[k * 512 + (n & 511)]);
  } else if (id < 786432 + 262144) {       // woT[n][k]
    long j = id - 786432, n = j >> 9, k = j & 511;
    woT[j] = f2bf(wo[k * 512 + n]);
  } else if (id < 786432 + 262144 + 1536) {
    long j = id - 786432 - 262144;
    bias[j] = (j < 512) ? bq[j] : (j < 1024 ? bk[j - 512] : bv[j - 1024]);
  } else if (id < 786432 + 262144 + 1536 + 256) {
    stats[id - 786432 - 262144 - 1536] = 0.f;
  } else if (id < 786432 + 262144 + 1536 + 256 + 16384) {
    lsum[id - 786432 - 262144 - 1536 - 256] = 0.f;   // 4 batches x 4096 rows
  }
}

// ---------------- GroupNorm pass 1: coalesced partial sums -----------------
__global__ __launch_bounds__(256) void gn_stats(const float* __restrict__ x,
                                                float* __restrict__ stats) {
  const int b = blockIdx.x >> 7, slab = blockIdx.x & 127;
  const float* xp = x + (long)b * 4096 * 512 + (long)slab * 32 * 512;
  const int tid = threadIdx.x;
  float s = 0.f, s2 = 0.f;
  for (int it = 0; it < 16; ++it) {
    int i = it * 256 + tid;
    float4 v = *(const float4*)(xp + (long)i * 4);
    s += v.x + v.y + v.z + v.w;
    s2 += v.x * v.x + v.y * v.y + v.z * v.z + v.w * v.w;
  }
  s += __shfl_xor(s, 1); s += __shfl_xor(s, 2);
  s2 += __shfl_xor(s2, 1); s2 += __shfl_xor(s2, 2);
  if ((tid & 3) == 0) {
    int g = (tid & 127) >> 2;
    atomicAdd(&stats[(b * 32 + g) * 2], s);
    atomicAdd(&stats[(b * 32 + g) * 2 + 1], s2);
  }
}

// ---------------- GroupNorm pass 2: normalize -> bf16 ----------------------
__global__ __launch_bounds__(256) void gn_apply(const float* __restrict__ x,
                                                const float* __restrict__ stats,
                                                const float* __restrict__ gamma,
                                                const float* __restrict__ beta,
                                                unsigned short* __restrict__ xn) {
  long id = (long)blockIdx.x * 256 + threadIdx.x;
  long a = id * 4;
  int b = (int)(id >> 19);
  int ch = (int)(a & 511);
  int g = ch >> 4;
  float s = stats[(b * 32 + g) * 2], s2 = stats[(b * 32 + g) * 2 + 1];
  float mean = s * (1.f / 65536.f);
  float rinv = rsqrtf(s2 * (1.f / 65536.f) - mean * mean + 1e-6f);
  float4 v = *(const float4*)(x + a);
  float4 gm = *(const float4*)(gamma + ch);
  float4 bt = *(const float4*)(beta + ch);
  ushort4 o;
  o.x = f2bf((v.x - mean) * rinv * gm.x + bt.x);
  o.y = f2bf((v.y - mean) * rinv * gm.y + bt.y);
  o.z = f2bf((v.z - mean) * rinv * gm.z + bt.z);
  o.w = f2bf((v.w - mean) * rinv * gm.w + bt.w);
  *(ushort4*)(xn + a) = o;
}

// ---------------- QKV (256x256 8-phase engine): xn * wqkvT^T ---------------
__global__ __launch_bounds__(512, 2) void qkv_kernel(
    const unsigned short* __restrict__ xn, const unsigned short* __restrict__ wqkvT,
    const float* __restrict__ bias, unsigned short* __restrict__ q,
    unsigned short* __restrict__ kk, unsigned short* __restrict__ vv) {
  __shared__ unsigned short lds[65536];   // 128 KB
  f32x4 acc[8][4] = {};
  const long tm = (long)blockIdx.x * 256, tn = (long)blockIdx.y * 256;
  gemm256_tile(xn + tm * 512, 512, wqkvT + tn * 512, 512, 8, lds, acc);
  const int lane = threadIdx.x & 63, wave = threadIdx.x >> 6;
  const int wm2 = wave >> 2, wn4 = wave & 3;
  const int lcol = lane & 15, lrb = (lane >> 4) * 4;
  const int region = (int)(tn >> 9);      // tile never straddles q/k/v
  unsigned short* dst = region == 0 ? q : (region == 1 ? kk : vv);
  const float sc = region == 0 ? QSCALE : 1.f;   // fold softmax*log2e into q
  float bv[4];
#pragma unroll
  for (int nf = 0; nf < 4; ++nf) bv[nf] = bias[tn + wn4 * 64 + nf * 16 + lcol];
#pragma unroll
  for (int mf = 0; mf < 8; ++mf)
#pragma unroll
    for (int nf = 0; nf < 4; ++nf) {
      long n = tn + wn4 * 64 + nf * 16 + lcol;
      long nloc = n & 511;
#pragma unroll
      for (int r = 0; r < 4; ++r) {
        long m = tm + wm2 * 128 + mf * 16 + lrb + r;
        dst[m * 512 + nloc] = f2bf((acc[mf][nf][r] + bv[nf]) * sc);
      }
    }
}

// ---------------- v [b*4096+j][c] -> vT [b*512+c][j] -----------------------
__global__ __launch_bounds__(256) void transpose_v(const unsigned short* __restrict__ v,
                                                   unsigned short* __restrict__ vT) {
  const int b = blockIdx.z;
  const long j0 = (long)blockIdx.x * 64, c0 = (long)blockIdx.y * 64;
  __shared__ unsigned short t[64][72];
  const int tc = (threadIdx.x & 15) * 4, tr = threadIdx.x >> 4;
  for (int rr = 0; rr < 64; rr += 16) {
    ushort4 u = *(const ushort4*)&v[((long)b * 4096 + j0 + tr + rr) * 512 + c0 + tc];
    t[tr + rr][tc] = u.x; t[tr + rr][tc + 1] = u.y;
    t[tr + rr][tc + 2] = u.z; t[tr + rr][tc + 3] = u.w;
  }
  __syncthreads();
  for (int rr = 0; rr < 64; rr += 16) {
    int c = tr + rr;
    ushort4 o;
    o.x = t[tc + 0][c]; o.y = t[tc + 1][c]; o.z = t[tc + 2][c]; o.w = t[tc + 3][c];
    *(ushort4*)&vT[((long)b * 512 + c0 + c) * 4096 + j0 + tc] = o;
  }
}

// ---------------- QK^T + exp2 + row-sum atomics (128x128 dbuf) -------------
// q carries 512^-0.5 * log2(e): exp2f is a bare v_exp_f32.  No XCD swizzle
// (R9: +15.5us when inputs are L3-resident), no NT stores (R11: hurt pv).
__global__ __launch_bounds__(256) void qkt_kernel(
    const unsigned short* __restrict__ q, const unsigned short* __restrict__ kk,
    unsigned short* __restrict__ probs, float* __restrict__ lsum, int b0) {
  GEMM_SHARED
  f32x4 acc[4][4] = {};
  const int z = blockIdx.z;
  const long bb = (long)(b0 + z) * 4096 * 512;
  const long tm = (long)blockIdx.x * 128, tn = (long)blockIdx.y * 128;
  gemm_tile(q + bb + tm * 512, 512, kk + bb + tn * 512, 512, 512, As0, As1, Bs0, Bs1, acc);
  EPILOG_SETUP
  unsigned short* out = probs + (long)z * 4096 * 4096;
  float* ls = lsum + (long)(b0 + z) * 4096;
  const long n0 = tn + wn + lcol4;
#pragma unroll
  for (int mt = 0; mt < 4; ++mt) {
    float rs[4];
#pragma unroll
    for (int r = 0; r < 4; ++r) {
      float e0 = exp2f(acc[mt][0][r]);
      float e1 = exp2f(acc[mt][1][r]);
      float e2 = exp2f(acc[mt][2][r]);
      float e3 = exp2f(acc[mt][3][r]);
      rs[r] = (e0 + e1) + (e2 + e3);
      ushort4 o;
      o.x = f2bf(e0); o.y = f2bf(e1); o.z = f2bf(e2); o.w = f2bf(e3);
      long m = tm + wm + mt * 16 + lrb + r;
      *(ushort4*)&out[m * 4096 + n0] = o;
    }
#pragma unroll
    for (int r = 0; r < 4; ++r) {
      float s = rs[r];
      s += __shfl_xor(s, 1); s += __shfl_xor(s, 2);
      s += __shfl_xor(s, 4); s += __shfl_xor(s, 8);
      if (lcol4 == 0) atomicAdd(&ls[tm + wm + mt * 16 + lrb + r], s);
    }
  }
}

// ---------------- PV full-K (batched): attn = (P @ V^T) / l, bf16 ----------
__global__ __launch_bounds__(256) void pv_kernel(
    const unsigned short* __restrict__ probs, const unsigned short* __restrict__ vT,
    const float* __restrict__ lsum, unsigned short* __restrict__ attn, int b0) {
  GEMM_SHARED
  f32x4 acc[4][4] = {};
  const int z = blockIdx.z;
  const long tm = (long)blockIdx.x * 128, tn = (long)blockIdx.y * 128;
  gemm_tile(probs + (long)z * 4096 * 4096 + tm * 4096, 4096,
            vT + (long)(b0 + z) * 512 * 4096 + tn * 4096, 4096,
            4096, As0, As1, Bs0, Bs1, acc);
  EPILOG_SETUP
  unsigned short* out = attn + (long)(b0 + z) * 4096 * 512;
  const float* ls = lsum + (long)(b0 + z) * 4096;
  const long n0 = tn + wn + lcol4;
#pragma unroll
  for (int mt = 0; mt < 4; ++mt)
#pragma unroll
    for (int r = 0; r < 4; ++r) {
      long m = tm + wm + mt * 16 + lrb + r;
      float inv = __builtin_amdgcn_rcpf(ls[m]);
      ushort4 o;
      o.x = f2bf(acc[mt][0][r] * inv); o.y = f2bf(acc[mt][1][r] * inv);
      o.z = f2bf(acc[mt][2][r] * inv); o.w = f2bf(acc[mt][3][r] * inv);
      *(ushort4*)&out[m * 512 + n0] = o;
    }
}

// ---------------- out projection + bias + residual -------------------------
__global__ __launch_bounds__(256) void proj_kernel(
    const unsigned short* __restrict__ attn, const unsigned short* __restrict__ woT,
    const float* __restrict__ bo, const float* __restrict__ x,
    float* __restrict__ out) {
  GEMM_SHARED
  f32x4 acc[4][4] = {};
  const long tm = (long)blockIdx.x * 128, tn = (long)blockIdx.y * 128;
  gemm_tile(attn + tm * 512, 512, woT + tn * 512, 512, 512, As0, As1, Bs0, Bs1, acc);
  EPILOG_SETUP
  const long n0 = tn + wn + lcol4;
  float4 bs = *(const float4*)&bo[n0];
#pragma unroll
  for (int mt = 0; mt < 4; ++mt)
#pragma unroll
    for (int r = 0; r < 4; ++r) {
      long m = tm + wm + mt * 16 + lrb + r;
      float4 xv = *(const float4*)&x[m * 512 + n0];
      float4 o;
      o.x = acc[mt][0][r] + bs.x + xv.x;
      o.y = acc[mt][1][r] + bs.y + xv.y;
      o.z = acc[mt][2][r] + bs.z + xv.z;
      o.w = acc[mt][3][r] + bs.w + xv.w;
      *(float4*)&((float*)out)[m * 512 + n0] = o;
    }
}

extern "C" void kernel_launch(void* const* d_in, const int* in_sizes, int n_in,
                              void* d_out, int out_size, void* d_ws, size_t ws_size,
                              hipStream_t stream) {
  const float* x     = (const float*)d_in[0];
  const float* gamma = (const float*)d_in[1];
  const float* beta  = (const float*)d_in[2];
  const float* wq    = (const float*)d_in[3];
  const float* bq    = (const float*)d_in[4];
  const float* wk    = (const float*)d_in[5];
  const float* bk    = (const float*)d_in[6];
  const float* wv    = (const float*)d_in[7];
  const float* bv    = (const float*)d_in[8];
  const float* wo    = (const float*)d_in[9];
  const float* bo    = (const float*)d_in[10];

  char* p = (char*)d_ws;
  auto take = [&](size_t bytes) { char* r = p; p += (bytes + 255) & ~(size_t)255; return r; };
  const long NTOK = 16384, C = 512, HW = 4096;
  // Reuse: attn <- xn (dead after qkv); vbuf <- probs (dead until qkt).
  unsigned short* xn    = (unsigned short*)take(NTOK * C * 2);
  unsigned short* q     = (unsigned short*)take(NTOK * C * 2);
  unsigned short* kbuf  = (unsigned short*)take(NTOK * C * 2);
  unsigned short* vT    = (unsigned short*)take(NTOK * C * 2);
  unsigned short* wqkvT = (unsigned short*)take(1536l * 512 * 2);
  unsigned short* woT   = (unsigned short*)take(512l * 512 * 2);
  float* bias           = (float*)take(1536 * 4);
  float* stats          = (float*)take(256 * 4);
  float* lsum           = (float*)take(16384 * 4);

  size_t fixed = (size_t)(p - (char*)d_ws);
  size_t per_nb = (size_t)HW * HW * 2 + 512;       // probs only (no partials)
  int NB = (ws_size >= fixed + 4 * per_nb) ? 4
         : (ws_size >= fixed + 2 * per_nb) ? 2 : 1;
  unsigned short* probs = (unsigned short*)take((size_t)NB * HW * HW * 2);
  unsigned short* attn  = xn;
  unsigned short* vbuf  = probs;  // probs region >= 33.5 MB for any NB; dead until qkt

  prep_kernel<<<4168, 256, 0, stream>>>(wq, wk, wv, wo, bq, bk, bv, wqkvT, woT,
                                        bias, stats, lsum);
  gn_stats<<<512, 256, 0, stream>>>(x, stats);
  gn_apply<<<8192, 256, 0, stream>>>(x, stats, gamma, beta, xn);

  qkv_kernel<<<dim3(64, 6), 512, 0, stream>>>(xn, wqkvT, bias, q, kbuf, vbuf);
  transpose_v<<<dim3(64, 8, 4), 256, 0, stream>>>(vbuf, vT);

  for (int b0 = 0; b0 < 4; b0 += NB) {
    qkt_kernel<<<dim3(32, 32, NB), 256, 0, stream>>>(q, kbuf, probs, lsum, b0);
    pv_kernel<<<dim3(32, 4, NB), 256, 0, stream>>>(probs, vT, lsum, attn, b0);
  }

  proj_kernel<<<dim3(128, 4), 256, 0, stream>>>(attn, woT, bo, x, (float*)d_out);
}

// Round 10
// 353.172 us; speedup vs baseline: 1.0222x; 1.0222x over previous
//
#include <hip/hip_runtime.h>
#include <stdint.h>

// AttentionBlock: GroupNorm(32) -> QKV -> full 4096x4096 attention per batch
// -> out projection + residual.  B=4, HW=4096, C=512.
// R14 = R13 + bookkeeping-time attack (~85us of the 361 is non-GEMM):
//  - transpose_v DELETED: qkv's 256x256 epilogue writes vT directly -- per
//    lane the 4 acc values at fixed n span 4 consecutive m (=token j), i.e.
//    a contiguous ushort4 in vT[c][j].  Bitwise-identical values.
//  - prep + gn_stats merged into one kernel (prep's 4102 blocks + 512 gn
//    slab blocks); stats/lsum zeroing via one hipMemsetAsync (contiguous in
//    workspace) so atomics never race the zeroing.
//  - qkt: 128x128 dbuf, no swizzle, plain stores (112.4us, 4x replicated).
//  - qkv: 256x256 8-phase, (row>>1)&3 conflict-free swizzle (0 conflicts).
//  - pv: full-K=4096 128x128 dbuf, lsum division in epilogue.  proj: dbuf.

typedef __attribute__((ext_vector_type(8))) short bf16x8;
typedef __attribute__((ext_vector_type(4))) float f32x4;

#define QSCALE 0.06376237087058025f           // 512^-0.5 * log2(e)

__device__ __forceinline__ unsigned short f2bf(float f) {
  unsigned int x = __float_as_uint(f);
  x += 0x7fffu + ((x >> 16) & 1u);
  return (unsigned short)(x >> 16);
}
__device__ __forceinline__ float bf2f(unsigned short u) {
  return __uint_as_float((unsigned int)u << 16);
}

__device__ __forceinline__ void gl_lds16(const void* g, void* l) {
  __builtin_amdgcn_global_load_lds(
      (__attribute__((address_space(1))) unsigned char*)g,
      (__attribute__((address_space(3))) unsigned char*)l, 16, 0, 0);
}

#define SBAR() asm volatile("s_barrier" ::: "memory")

// ======== 128x128 dbuf engine (R6): B col-remap, 2-phase pipeline ==========
// LDS 16B granules XOR-swizzled: A by (row&7), B by ((row>>2)&7).
// B fragment t covers cols wn + 4*lrow + t  =>  vectorized epilogues
// (acc[mt][t][r] = C[wm+mt*16+lrb+r][wn+4*lcol+t]).
__device__ __forceinline__ void gemm_tile(
    const unsigned short* __restrict__ A, long lda,
    const unsigned short* __restrict__ B, long ldb,
    int K,
    unsigned short* As0, unsigned short* As1,
    unsigned short* Bs0, unsigned short* Bs1,
    f32x4 acc[4][4]) {
  const int tid = threadIdx.x;
  const int wave = tid >> 6, lane = tid & 63;
  const int srow = lane >> 3;
  const int gg = lane & 7;
  const int wm = (wave >> 1) * 64, wn = (wave & 1) * 64;
  const int lrow = lane & 15;
  const int rsw = lrow & 7;
  const int kgb = lane >> 4;

  auto STAGE = [&](unsigned short* as, unsigned short* bs, int k0) {
#pragma unroll
    for (int i = 0; i < 4; ++i) {
      int chunk = wave * 4 + i;
      int row = chunk * 8 + srow;
      int soffA = (gg ^ srow) * 16;
      int soffB = (gg ^ ((chunk * 2 + (srow >> 2)) & 7)) * 16;
      gl_lds16((const char*)(A + (long)row * lda + k0) + soffA, (char*)as + chunk * 1024);
      gl_lds16((const char*)(B + (long)row * ldb + k0) + soffB, (char*)bs + chunk * 1024);
    }
  };

  auto COMPUTE = [&](const unsigned short* as, const unsigned short* bs) {
#pragma unroll
    for (int ks = 0; ks < 2; ++ks) {
      bf16x8 af[4], bfr[4];
      const int off = ((ks * 4 + kgb) ^ rsw) * 8;
#pragma unroll
      for (int t = 0; t < 4; ++t) {
        af[t]  = *(const bf16x8*)&as[(wm + t * 16 + lrow) * 64 + off];
        bfr[t] = *(const bf16x8*)&bs[(wn + 4 * lrow + t) * 64 + off];
      }
#pragma unroll
      for (int mt = 0; mt < 4; ++mt)
#pragma unroll
        for (int nt = 0; nt < 4; ++nt)
          acc[mt][nt] = __builtin_amdgcn_mfma_f32_16x16x32_bf16(af[mt], bfr[nt], acc[mt][nt], 0, 0, 0);
    }
  };

  const int nk = K >> 6;
  STAGE(As0, Bs0, 0);
  __syncthreads();
  for (int t = 0; t < nk; t += 2) {
    if (t + 1 < nk) STAGE(As1, Bs1, (t + 1) * 64);
    COMPUTE(As0, Bs0);
    __syncthreads();
    if (t + 2 < nk) STAGE(As0, Bs0, (t + 2) * 64);
    COMPUTE(As1, Bs1);
    __syncthreads();
  }
}

#define GEMM_SHARED                                              \
  __shared__ unsigned short As0[128 * 64], As1[128 * 64];        \
  __shared__ unsigned short Bs0[128 * 64], Bs1[128 * 64];

#define EPILOG_SETUP                                          \
  const int lane = threadIdx.x & 63, wave = threadIdx.x >> 6; \
  const int wm = (wave >> 1) * 64, wn = (wave & 1) * 64;      \
  const int lcol4 = (lane & 15) * 4, lrb = (lane >> 4) * 4;

// ================= 256x256 tile, BK=64, 2-dbuf K-halves, 8-phase ============
// Conflict-free swizzle: bank = (16*row + 4*slot) % 32; key = (row>>1)&3
// gives every bank exactly 2 lanes per 16-lane group (free, m136); key
// invariant under row+16/+64/+128 so one key serves staging and reads.
// Counted vmcnt(8) gates, never vmcnt(0) in steady state.
__device__ __forceinline__ void gemm256_tile(
    const unsigned short* __restrict__ A, long lda,
    const unsigned short* __restrict__ B, long ldb,
    int NT, unsigned short* lds, f32x4 acc[8][4]) {
  const int tid = threadIdx.x;
  const int wave = tid >> 6, lane = tid & 63;
  const int wm = wave >> 2, wn = wave & 3;
  const int lrow = lane & 15, kgb = lane >> 4;
  const int koff = (kgb ^ ((lrow >> 1) & 3)) * 8;       // key=(row>>1)&3
  const int srow = wave * 32 + (lane >> 2);
  const int sg = ((lane & 3) ^ ((lane >> 3) & 3)) * 8;  // key(srow>>1)&3 == (lane>>3)&3
  const int sdst = wave * 1024;

  auto STAGE = [&](int t, int kh, int isB) {
    const unsigned short* src = (isB ? B : A) + (long)t * 64 + kh * 32 + sg;
    long ld = isB ? ldb : lda;
    unsigned short* db = lds + isB * 32768 + ((t & 1) * 2 + kh) * 8192 + sdst;
    gl_lds16(src + (long)srow * ld, db);
    gl_lds16(src + (long)(srow + 16) * ld, db + 512);   // key(row+16)==key(row)
  };

  STAGE(0, 0, 0); STAGE(0, 0, 1);
  STAGE(0, 1, 0); STAGE(0, 1, 1);
  STAGE(1, 0, 0); STAGE(1, 0, 1);

  for (int T = 0; T < NT; ++T) {
    const int d2 = (T & 1) * 2;
    const unsigned short* aB = lds + d2 * 8192 + (wm * 128 + lrow) * 32 + koff;
    const unsigned short* bB = lds + 32768 + d2 * 8192 + ((wn & 1) * 64 + lrow) * 32 + koff;
    const bool more = (T + 1 < NT);
    bf16x8 a0[4], a1[4], b0[4];

    if (more) { asm volatile("s_waitcnt vmcnt(8)" ::: "memory"); }
    else      { asm volatile("s_waitcnt vmcnt(4)" ::: "memory"); }
    SBAR();

#pragma unroll
    for (int m = 0; m < 4; ++m) a0[m] = *(const bf16x8*)(aB + m * 512);
#pragma unroll
    for (int n = 0; n < 4; ++n) b0[n] = *(const bf16x8*)(bB + n * 512);
    if (more) STAGE(T + 1, 1, 0);
    SBAR();
    __builtin_amdgcn_s_setprio(1);
#pragma unroll
    for (int m = 0; m < 4; ++m)
#pragma unroll
      for (int n = 0; n < 4; ++n)
        acc[m][n] = __builtin_amdgcn_mfma_f32_16x16x32_bf16(a0[m], b0[n], acc[m][n], 0, 0, 0);
    __builtin_amdgcn_s_setprio(0);

#pragma unroll
    for (int m = 0; m < 4; ++m) a1[m] = *(const bf16x8*)(aB + (4 + m) * 512);
    if (more) STAGE(T + 1, 1, 1);
    SBAR();
    __builtin_amdgcn_s_setprio(1);
#pragma unroll
    for (int m = 0; m < 4; ++m)
#pragma unroll
      for (int n = 0; n < 4; ++n)
        acc[4 + m][n] = __builtin_amdgcn_mfma_f32_16x16x32_bf16(a1[m], b0[n], acc[4 + m][n], 0, 0, 0);
    __builtin_amdgcn_s_setprio(0);

    if (more) { asm volatile("s_waitcnt vmcnt(8)" ::: "memory"); }
    else      { asm volatile("s_waitcnt vmcnt(0)" ::: "memory"); }
    SBAR();

    const unsigned short* aB1 = aB + 8192;
    const unsigned short* bB1 = bB + 8192;
#pragma unroll
    for (int m = 0; m < 4; ++m) a0[m] = *(const bf16x8*)(aB1 + m * 512);
#pragma unroll
    for (int n = 0; n < 4; ++n) b0[n] = *(const bf16x8*)(bB1 + n * 512);
    if (T + 2 < NT) STAGE(T + 2, 0, 0);
    SBAR();
    __builtin_amdgcn_s_setprio(1);
#pragma unroll
    for (int m = 0; m < 4; ++m)
#pragma unroll
      for (int n = 0; n < 4; ++n)
        acc[m][n] = __builtin_amdgcn_mfma_f32_16x16x32_bf16(a0[m], b0[n], acc[m][n], 0, 0, 0);
    __builtin_amdgcn_s_setprio(0);
    SBAR();

#pragma unroll
    for (int m = 0; m < 4; ++m) a1[m] = *(const bf16x8*)(aB1 + (4 + m) * 512);
    if (T + 2 < NT) STAGE(T + 2, 0, 1);
    SBAR();
    __builtin_amdgcn_s_setprio(1);
#pragma unroll
    for (int m = 0; m < 4; ++m)
#pragma unroll
      for (int n = 0; n < 4; ++n)
        acc[4 + m][n] = __builtin_amdgcn_mfma_f32_16x16x32_bf16(a1[m], b0[n], acc[4 + m][n], 0, 0, 0);
    __builtin_amdgcn_s_setprio(0);
  }
}

// ------- merged prep (weights->bf16, bias pack) + GroupNorm stats ----------
// Blocks [0,4102): prep ids 0..1050112 (wqkvT 786432 | woT 262144 | bias 1536).
// Blocks [4102,4614): gn_stats slabs.  stats/lsum are pre-zeroed by a
// hipMemsetAsync on the stream (ordering vs the atomics is guaranteed).
__global__ __launch_bounds__(256) void prep_gn(
    const float* __restrict__ wq, const float* __restrict__ wk,
    const float* __restrict__ wv, const float* __restrict__ wo,
    const float* __restrict__ bq, const float* __restrict__ bk,
    const float* __restrict__ bv, const float* __restrict__ x,
    unsigned short* __restrict__ wqkvT, unsigned short* __restrict__ woT,
    float* __restrict__ bias, float* __restrict__ stats) {
  if (blockIdx.x < 4102) {
    long id = (long)blockIdx.x * 256 + threadIdx.x;
    if (id < 786432) {                       // wqkvT[n][k]
      long n = id >> 9, k = id & 511;
      const float* w = (n < 512) ? wq : (n < 1024 ? wk : wv);
      wqkvT[id] = f2bf(w[k * 512 + (n & 511)]);
    } else if (id < 786432 + 262144) {       // woT[n][k]
      long j = id - 786432, n = j >> 9, k = j & 511;
      woT[j] = f2bf(wo[k * 512 + n]);
    } else {                                 // bias pack (exactly 1536)
      long j = id - 786432 - 262144;
      bias[j] = (j < 512) ? bq[j] : (j < 1024 ? bk[j - 512] : bv[j - 1024]);
    }
    return;
  }
  const int bI = blockIdx.x - 4102;
  const int b = bI >> 7, slab = bI & 127;
  const float* xp = x + (long)b * 4096 * 512 + (long)slab * 32 * 512;
  const int tid = threadIdx.x;
  float s = 0.f, s2 = 0.f;
  for (int it = 0; it < 16; ++it) {
    int i = it * 256 + tid;
    float4 v = *(const float4*)(xp + (long)i * 4);
    s += v.x + v.y + v.z + v.w;
    s2 += v.x * v.x + v.y * v.y + v.z * v.z + v.w * v.w;
  }
  s += __shfl_xor(s, 1); s += __shfl_xor(s, 2);
  s2 += __shfl_xor(s2, 1); s2 += __shfl_xor(s2, 2);
  if ((tid & 3) == 0) {
    int g = (tid & 127) >> 2;
    atomicAdd(&stats[(b * 32 + g) * 2], s);
    atomicAdd(&stats[(b * 32 + g) * 2 + 1], s2);
  }
}

// ---------------- GroupNorm pass 2: normalize -> bf16 ----------------------
__global__ __launch_bounds__(256) void gn_apply(const float* __restrict__ x,
                                                const float* __restrict__ stats,
                                                const float* __restrict__ gamma,
                                                const float* __restrict__ beta,
                                                unsigned short* __restrict__ xn) {
  long id = (long)blockIdx.x * 256 + threadIdx.x;
  long a = id * 4;
  int b = (int)(id >> 19);
  int ch = (int)(a & 511);
  int g = ch >> 4;
  float s = stats[(b * 32 + g) * 2], s2 = stats[(b * 32 + g) * 2 + 1];
  float mean = s * (1.f / 65536.f);
  float rinv = rsqrtf(s2 * (1.f / 65536.f) - mean * mean + 1e-6f);
  float4 v = *(const float4*)(x + a);
  float4 gm = *(const float4*)(gamma + ch);
  float4 bt = *(const float4*)(beta + ch);
  ushort4 o;
  o.x = f2bf((v.x - mean) * rinv * gm.x + bt.x);
  o.y = f2bf((v.y - mean) * rinv * gm.y + bt.y);
  o.z = f2bf((v.z - mean) * rinv * gm.z + bt.z);
  o.w = f2bf((v.w - mean) * rinv * gm.w + bt.w);
  *(ushort4*)(xn + a) = o;
}

// ---------------- QKV (256x256 8-phase engine): xn * wqkvT^T ---------------
// v region (tn>=1024) writes vT[c][j] DIRECTLY: acc[mf][nf][0..3] are 4
// consecutive m (=j) at fixed n -> contiguous ushort4 (j%4==0 => 8B aligned).
__global__ __launch_bounds__(512, 2) void qkv_kernel(
    const unsigned short* __restrict__ xn, const unsigned short* __restrict__ wqkvT,
    const float* __restrict__ bias, unsigned short* __restrict__ q,
    unsigned short* __restrict__ kk, unsigned short* __restrict__ vT) {
  __shared__ unsigned short lds[65536];   // 128 KB
  f32x4 acc[8][4] = {};
  const long tm = (long)blockIdx.x * 256, tn = (long)blockIdx.y * 256;
  gemm256_tile(xn + tm * 512, 512, wqkvT + tn * 512, 512, 8, lds, acc);
  const int lane = threadIdx.x & 63, wave = threadIdx.x >> 6;
  const int wm2 = wave >> 2, wn4 = wave & 3;
  const int lcol = lane & 15, lrb = (lane >> 4) * 4;
  const int region = (int)(tn >> 9);      // tile never straddles q/k/v
  float bv[4];
#pragma unroll
  for (int nf = 0; nf < 4; ++nf) bv[nf] = bias[tn + wn4 * 64 + nf * 16 + lcol];
  if (region < 2) {
    unsigned short* dst = region == 0 ? q : kk;
    const float sc = region == 0 ? QSCALE : 1.f;   // fold softmax*log2e into q
#pragma unroll
    for (int mf = 0; mf < 8; ++mf)
#pragma unroll
      for (int nf = 0; nf < 4; ++nf) {
        long nloc = (tn + wn4 * 64 + nf * 16 + lcol) & 511;
#pragma unroll
        for (int r = 0; r < 4; ++r) {
          long m = tm + wm2 * 128 + mf * 16 + lrb + r;
          dst[m * 512 + nloc] = f2bf((acc[mf][nf][r] + bv[nf]) * sc);
        }
      }
  } else {
#pragma unroll
    for (int mf = 0; mf < 8; ++mf)
#pragma unroll
      for (int nf = 0; nf < 4; ++nf) {
        long c = (tn + wn4 * 64 + nf * 16 + lcol) - 1024;
        long m = tm + wm2 * 128 + mf * 16 + lrb;     // 4 consecutive tokens
        long b = m >> 12, j = m & 4095;
        ushort4 o;
        o.x = f2bf(acc[mf][nf][0] + bv[nf]);
        o.y = f2bf(acc[mf][nf][1] + bv[nf]);
        o.z = f2bf(acc[mf][nf][2] + bv[nf]);
        o.w = f2bf(acc[mf][nf][3] + bv[nf]);
        *(ushort4*)&vT[(b * 512 + c) * 4096 + j] = o;
      }
  }
}

// ---------------- QK^T + exp2 + row-sum atomics (128x128 dbuf) -------------
// q carries 512^-0.5 * log2(e): exp2f is a bare v_exp_f32.  No XCD swizzle
// (R9: +15.5us when inputs are L3-resident), no NT stores (R11: hurt pv).
__global__ __launch_bounds__(256) void qkt_kernel(
    const unsigned short* __restrict__ q, const unsigned short* __restrict__ kk,
    unsigned short* __restrict__ probs, float* __restrict__ lsum, int b0) {
  GEMM_SHARED
  f32x4 acc[4][4] = {};
  const int z = blockIdx.z;
  const long bb = (long)(b0 + z) * 4096 * 512;
  const long tm = (long)blockIdx.x * 128, tn = (long)blockIdx.y * 128;
  gemm_tile(q + bb + tm * 512, 512, kk + bb + tn * 512, 512, 512, As0, As1, Bs0, Bs1, acc);
  EPILOG_SETUP
  unsigned short* out = probs + (long)z * 4096 * 4096;
  float* ls = lsum + (long)(b0 + z) * 4096;
  const long n0 = tn + wn + lcol4;
#pragma unroll
  for (int mt = 0; mt < 4; ++mt) {
    float rs[4];
#pragma unroll
    for (int r = 0; r < 4; ++r) {
      float e0 = exp2f(acc[mt][0][r]);
      float e1 = exp2f(acc[mt][1][r]);
      float e2 = exp2f(acc[mt][2][r]);
      float e3 = exp2f(acc[mt][3][r]);
      rs[r] = (e0 + e1) + (e2 + e3);
      ushort4 o;
      o.x = f2bf(e0); o.y = f2bf(e1); o.z = f2bf(e2); o.w = f2bf(e3);
      long m = tm + wm + mt * 16 + lrb + r;
      *(ushort4*)&out[m * 4096 + n0] = o;
    }
#pragma unroll
    for (int r = 0; r < 4; ++r) {
      float s = rs[r];
      s += __shfl_xor(s, 1); s += __shfl_xor(s, 2);
      s += __shfl_xor(s, 4); s += __shfl_xor(s, 8);
      if (lcol4 == 0) atomicAdd(&ls[tm + wm + mt * 16 + lrb + r], s);
    }
  }
}

// ---------------- PV full-K (batched): attn = (P @ V^T) / l, bf16 ----------
__global__ __launch_bounds__(256) void pv_kernel(
    const unsigned short* __restrict__ probs, const unsigned short* __restrict__ vT,
    const float* __restrict__ lsum, unsigned short* __restrict__ attn, int b0) {
  GEMM_SHARED
  f32x4 acc[4][4] = {};
  const int z = blockIdx.z;
  const long tm = (long)blockIdx.x * 128, tn = (long)blockIdx.y * 128;
  gemm_tile(probs + (long)z * 4096 * 4096 + tm * 4096, 4096,
            vT + (long)(b0 + z) * 512 * 4096 + tn * 4096, 4096,
            4096, As0, As1, Bs0, Bs1, acc);
  EPILOG_SETUP
  unsigned short* out = attn + (long)(b0 + z) * 4096 * 512;
  const float* ls = lsum + (long)(b0 + z) * 4096;
  const long n0 = tn + wn + lcol4;
#pragma unroll
  for (int mt = 0; mt < 4; ++mt)
#pragma unroll
    for (int r = 0; r < 4; ++r) {
      long m = tm + wm + mt * 16 + lrb + r;
      float inv = __builtin_amdgcn_rcpf(ls[m]);
      ushort4 o;
      o.x = f2bf(acc[mt][0][r] * inv); o.y = f2bf(acc[mt][1][r] * inv);
      o.z = f2bf(acc[mt][2][r] * inv); o.w = f2bf(acc[mt][3][r] * inv);
      *(ushort4*)&out[m * 512 + n0] = o;
    }
}

// ---------------- out projection + bias + residual -------------------------
__global__ __launch_bounds__(256) void proj_kernel(
    const unsigned short* __restrict__ attn, const unsigned short* __restrict__ woT,
    const float* __restrict__ bo, const float* __restrict__ x,
    float* __restrict__ out) {
  GEMM_SHARED
  f32x4 acc[4][4] = {};
  const long tm = (long)blockIdx.x * 128, tn = (long)blockIdx.y * 128;
  gemm_tile(attn + tm * 512, 512, woT + tn * 512, 512, 512, As0, As1, Bs0, Bs1, acc);
  EPILOG_SETUP
  const long n0 = tn + wn + lcol4;
  float4 bs = *(const float4*)&bo[n0];
#pragma unroll
  for (int mt = 0; mt < 4; ++mt)
#pragma unroll
    for (int r = 0; r < 4; ++r) {
      long m = tm + wm + mt * 16 + lrb + r;
      float4 xv = *(const float4*)&x[m * 512 + n0];
      float4 o;
      o.x = acc[mt][0][r] + bs.x + xv.x;
      o.y = acc[mt][1][r] + bs.y + xv.y;
      o.z = acc[mt][2][r] + bs.z + xv.z;
      o.w = acc[mt][3][r] + bs.w + xv.w;
      *(float4*)&((float*)out)[m * 512 + n0] = o;
    }
}

extern "C" void kernel_launch(void* const* d_in, const int* in_sizes, int n_in,
                              void* d_out, int out_size, void* d_ws, size_t ws_size,
                              hipStream_t stream) {
  const float* x     = (const float*)d_in[0];
  const float* gamma = (const float*)d_in[1];
  const float* beta  = (const float*)d_in[2];
  const float* wq    = (const float*)d_in[3];
  const float* bq    = (const float*)d_in[4];
  const float* wk    = (const float*)d_in[5];
  const float* bk    = (const float*)d_in[6];
  const float* wv    = (const float*)d_in[7];
  const float* bv    = (const float*)d_in[8];
  const float* wo    = (const float*)d_in[9];
  const float* bo    = (const float*)d_in[10];

  char* p = (char*)d_ws;
  auto take = [&](size_t bytes) { char* r = p; p += (bytes + 255) & ~(size_t)255; return r; };
  const long NTOK = 16384, C = 512, HW = 4096;
  // Reuse: attn <- xn (dead after qkv).
  unsigned short* xn    = (unsigned short*)take(NTOK * C * 2);
  unsigned short* q     = (unsigned short*)take(NTOK * C * 2);
  unsigned short* kbuf  = (unsigned short*)take(NTOK * C * 2);
  unsigned short* vT    = (unsigned short*)take(NTOK * C * 2);
  unsigned short* wqkvT = (unsigned short*)take(1536l * 512 * 2);
  unsigned short* woT   = (unsigned short*)take(512l * 512 * 2);
  float* bias           = (float*)take(1536 * 4);
  float* stats          = (float*)take(256 * 4);     // 1024 B
  float* lsum           = (float*)take(16384 * 4);   // contiguous after stats

  size_t fixed = (size_t)(p - (char*)d_ws);
  size_t per_nb = (size_t)HW * HW * 2 + 512;       // probs only (no partials)
  int NB = (ws_size >= fixed + 4 * per_nb) ? 4
         : (ws_size >= fixed + 2 * per_nb) ? 2 : 1;
  unsigned short* probs = (unsigned short*)take((size_t)NB * HW * HW * 2);
  unsigned short* attn  = xn;

  // zero stats (1KB) + lsum (64KB): contiguous, one memset; must complete
  // before prep_gn's atomics (stream order guarantees it).
  hipMemsetAsync(stats, 0, 1024 + 16384 * 4, stream);

  prep_gn<<<4614, 256, 0, stream>>>(wq, wk, wv, wo, bq, bk, bv, x,
                                    wqkvT, woT, bias, stats);
  gn_apply<<<8192, 256, 0, stream>>>(x, stats, gamma, beta, xn);

  qkv_kernel<<<dim3(64, 6), 512, 0, stream>>>(xn, wqkvT, bias, q, kbuf, vT);

  for (int b0 = 0; b0 < 4; b0 += NB) {
    qkt_kernel<<<dim3(32, 32, NB), 256, 0, stream>>>(q, kbuf, probs, lsum, b0);
    pv_kernel<<<dim3(32, 4, NB), 256, 0, stream>>>(probs, vT, lsum, attn, b0);
  }

  proj_kernel<<<dim3(128, 4), 256, 0, stream>>>(attn, woT, bo, x, (float*)d_out);
}